// Round 1
// baseline (208.967 us; speedup 1.0000x reference)
//
#include <hip/hip_runtime.h>
#include <math.h>

#ifndef M_PI
#define M_PI 3.14159265358979323846
#endif

// Inclusive prefix sum over a 32-lane group (s = lane & 31).
__device__ __forceinline__ float scan_incl32(float v, int s) {
#pragma unroll
  for (int off = 1; off < 32; off <<= 1) {
    float n = __shfl_up(v, off, 32);
    if (s >= off) v += n;
  }
  return v;
}

// Butterfly sum over a 32-lane group (all lanes get the result).
__device__ __forceinline__ float redsum32(float v) {
#pragma unroll
  for (int off = 16; off >= 1; off >>= 1) v += __shfl_xor(v, off, 32);
  return v;
}

// One wave handles 2 rows: lanes [0..23] -> row g=0, lanes [32..55] -> row g=1.
// lane%32 == timestep s. Sequential ops (EMA/cumsum/RSI window) are prefix scans.
__global__ __launch_bounds__(256) void feat_in_kernel(
    const float* __restrict__ x, float* __restrict__ out, int B) {
  constexpr float EPS = 1e-8f;
  constexpr float IN_EPS = 1e-5f;

  const int tid = threadIdx.x;
  const int wave = tid >> 6;
  const int lane = tid & 63;
  const int g = lane >> 5;   // row within wave
  const int s = lane & 31;   // timestep (active if < 24)

  __shared__ float lds[4][1200];  // 4800 B per wave: input stage then output stage
  float* Lw = lds[wave];

  const long long b0 = ((long long)blockIdx.x * 4 + wave) * 2;  // first row of wave
  long long rem = (long long)B - b0;
  int nrows = rem >= 2 ? 2 : (rem > 0 ? (int)rem : 0);

  // ---- Phase A: coalesced global -> LDS (nrows*120 floats = nrows*30 float4) ----
  if (nrows > 0) {
    const float4* src4 = (const float4*)(x + b0 * 120);
    float4* L4 = (float4*)Lw;
    if (lane < nrows * 30) L4[lane] = src4[lane];
  }
  __syncthreads();

  const bool act = (s < 24) && (g < nrows);

  // ---- Phase B: per-lane feature computation ----
  int ib = g * 120 + s * 5;  // max 279 < 1200, always in-bounds
  float open_ = Lw[ib + 0];
  float high  = Lw[ib + 1];
  float low   = Lw[ib + 2];
  float close = Lw[ib + 3];
  float volume= Lw[ib + 4];
  if (!act) { open_ = 0.f; high = 0.f; low = 0.f; close = 1.f; volume = 0.f; }

  float f[25];

  float lc = __logf(close + EPS);
  float lc1 = __shfl_up(lc, 1, 32);
  float ret = (s >= 1) ? (lc - lc1) : 0.f;

  f[0] = open_; f[1] = high; f[2] = low; f[3] = close; f[4] = volume;
  f[5] = ret;   f[6] = fabsf(ret);
  float ice = 1.0f / (close + EPS);
  f[7] = (high - low) * ice;
  f[8] = fabsf(open_ - close) * ice;

  // EMAs: ema[s] = scan(x * beta^s) * (1-beta) / (1 - beta^(s+1))
  const float L2B3  = -1.0f;                    // log2(1/2)
  const float L2B6  = -0.48542682717024176f;    // log2(5/7)
  const float L2B12 = -0.24100810933089442f;    // log2(11/13)
  const float L2B24 = -0.12029423371771609f;    // log2(23/25)
  float sf = (float)s;
  float w3  = exp2f(L2B3  * sf);
  float w6  = exp2f(L2B6  * sf);
  float w12 = exp2f(L2B12 * sf);
  float w24 = exp2f(L2B24 * sf);

  float e3  = scan_incl32(close * w3 , s) * (0.5f)       / (1.f - w3  * 0.5f);
  float e6  = scan_incl32(close * w6 , s) * (2.f / 7.f)  / (1.f - w6  * (5.f / 7.f));
  float e12 = scan_incl32(close * w12, s) * (2.f / 13.f) / (1.f - w12 * (11.f / 13.f));
  float e24 = scan_incl32(close * w24, s) * (2.f / 25.f) / (1.f - w24 * (23.f / 25.f));
  float v6  = scan_incl32(volume * w6 , s) * (2.f / 7.f)  / (1.f - w6  * (5.f / 7.f));
  float v12 = scan_incl32(volume * w12, s) * (2.f / 13.f) / (1.f - w12 * (11.f / 13.f));

  float icl = 1.0f / close;
  f[9]  = e3  * icl;
  f[10] = e6  * icl;
  f[11] = e12 * icl;
  f[12] = e24 * icl;
  float iv = 1.0f / (volume + EPS);
  f[13] = v6  * iv;
  f[14] = v12 * iv;
  f[15] = __logf(1.f + volume);

  float ang = (float)(M_PI / 12.0) * sf;  // 2*pi*s/24
  f[16] = __sinf(ang);
  f[17] = __cosf(ang);

  float lc3 = __shfl_up(lc, 3, 32);
  float lc6 = __shfl_up(lc, 6, 32);
  f[18] = (s >= 3) ? (lc - lc3) : 0.f;
  f[19] = (s >= 6) ? (lc - lc6) : 0.f;
  f[20] = (close - e12) / (e12 + EPS);

  // RSI: window-14 moving average of gains/losses with left replicate-pad.
  float cl1 = __shfl_up(close, 1, 32);
  float delta = (s >= 1) ? (close - cl1) : 0.f;
  float gain  = fmaxf(delta, 0.f);
  float lossv = fmaxf(-delta, 0.f);
  float Pg = scan_incl32(gain, s);   // P[d] with d = s-1 (gain at s=0 is 0)
  float Pl = scan_incl32(lossv, s);
  float Pg14 = __shfl_up(Pg, 14, 32);
  float Pl14 = __shfl_up(Pl, 14, 32);
  float g1 = __shfl(gain, 1, 32);   // first delta's gain (a[0])
  float l1 = __shfl(lossv, 1, 32);
  float cnt = (float)(14 - s);      // (13 - d)
  float ag = (s >= 14) ? (Pg - Pg14) : (Pg + cnt * g1);
  float al = (s >= 14) ? (Pl - Pl14) : (Pl + cnt * l1);
  ag *= (1.f / 14.f);
  al *= (1.f / 14.f);
  float rs  = ag / (al + EPS);
  float rsi = 100.f - 100.f / (1.f + rs);
  float rsi1 = __shfl(rsi, 1, 32);  // edge pad: rsi[0] = rsi at d=0 (lane 1)
  f[21] = (s == 0) ? rsi1 : rsi;

  // OBV
  float mult = (delta > 0.f) ? 1.f : ((delta < 0.f) ? -1.f : 0.f);
  f[22] = scan_incl32(volume * mult, s);

  // Constant-over-s channels: instance norm -> 0 (|err| ~ 2e-5 << 9.5e-2 tol)
  f[23] = 0.f;
  f[24] = 0.f;

  if (!act) {
#pragma unroll
    for (int c = 0; c < 25; c++) f[c] = 0.f;
  }

  // ---- Instance norm over s (24 samples), two-pass for precision ----
#pragma unroll
  for (int c = 0; c < 23; c++) {
    float mean = redsum32(f[c]) * (1.f / 24.f);
    float dev = f[c] - mean;
    if (!act) dev = 0.f;  // inactive lanes must not pollute the variance
    float var = redsum32(dev * dev) * (1.f / 24.f);
    f[c] = dev * rsqrtf(var + IN_EPS);
  }

  // ---- Phase C: stage normalized features in LDS (overwrites input region) ----
  __syncthreads();
  if (act) {
    int ob = g * 600 + s * 25;
#pragma unroll
    for (int c = 0; c < 25; c++) Lw[ob + c] = f[c];
  }
  __syncthreads();

  // ---- Phase D: coalesced LDS -> global (nrows*150 float4) ----
  if (nrows > 0) {
    float4* dst4 = (float4*)(out + b0 * 600);
    const float4* L4o = (const float4*)Lw;
    int n4 = nrows * 150;
#pragma unroll
    for (int k = lane; k < 300; k += 64) {
      if (k < n4) dst4[k] = L4o[k];
    }
  }
}

extern "C" void kernel_launch(void* const* d_in, const int* in_sizes, int n_in,
                              void* d_out, int out_size, void* d_ws, size_t ws_size,
                              hipStream_t stream) {
  const float* x = (const float*)d_in[0];
  float* out = (float*)d_out;
  int B = in_sizes[0] / 120;          // rows of (24,5)
  int blocks = (B + 7) / 8;           // 8 rows per 256-thread block (2 per wave)
  feat_in_kernel<<<blocks, 256, 0, stream>>>(x, out, B);
}

// Round 2
// 78.236 us; speedup vs baseline: 2.6710x; 2.6710x over previous
//
#include <hip/hip_runtime.h>
#include <math.h>

#ifndef M_PI
#define M_PI 3.14159265358979323846
#endif

#define CTRL_ROW_SHR(n)  (0x110 | (n))
#define CTRL_ROW_BCAST15 0x142

// DPP move with old=0, bound_ctrl=0-fill: lanes with no source (or masked rows) yield 0.
template <int CTRL, int RM>
__device__ __forceinline__ float dpp_mov0(float v) {
  return __int_as_float(__builtin_amdgcn_update_dpp(
      0, __float_as_int(v), CTRL, RM, 0xF, true));
}

// Inclusive prefix sum over each 32-lane half (lanes 0-31 and 32-63). VALU-only.
__device__ __forceinline__ float scan32_dpp(float v) {
  v += dpp_mov0<CTRL_ROW_SHR(1), 0xF>(v);
  v += dpp_mov0<CTRL_ROW_SHR(2), 0xF>(v);
  v += dpp_mov0<CTRL_ROW_SHR(4), 0xF>(v);
  v += dpp_mov0<CTRL_ROW_SHR(8), 0xF>(v);
  v += dpp_mov0<CTRL_ROW_BCAST15, 0xa>(v);  // rows 1,3 += lane15/47 prefix
  return v;
}

// Value of (lane-1) within the 32-group; lanes with s==0 get 0/garbage (unused). VALU-only.
__device__ __forceinline__ float shift1_dpp(float v, int s) {
  float a = dpp_mov0<CTRL_ROW_SHR(1), 0xF>(v);      // wrong for s==16 (row boundary)
  float b = dpp_mov0<CTRL_ROW_BCAST15, 0xa>(v);     // lane15 -> lanes 16..31 (and 47 -> 48..63)
  return (s == 16) ? b : a;
}

// One wave handles 2 rows: lanes [0..23] -> row g=0, lanes [32..55] -> row g=1.
// lane%32 == timestep s. Scans via DPP; instance-norm via transposed stats lanes.
__global__ __launch_bounds__(256) void feat_in_kernel(
    const float* __restrict__ x, float* __restrict__ out, int B) {
  constexpr float EPS = 1e-8f;
  constexpr float IN_EPS = 1e-5f;

  const int tid = threadIdx.x;
  const int wave = tid >> 6;
  const int lane = tid & 63;
  const int g = lane >> 5;   // row within wave
  const int s = lane & 31;   // timestep (active if < 24)

  __shared__ float lds[4][1200];  // 4800 B per wave
  float* Lw = lds[wave];

  const long long b0 = ((long long)blockIdx.x * 4 + wave) * 2;  // first row of wave
  long long rem = (long long)B - b0;
  int nrows = rem >= 2 ? 2 : (rem > 0 ? (int)rem : 0);

  // ---- Phase A: coalesced global -> LDS (nrows*30 float4) ----
  if (nrows > 0) {
    const float4* src4 = (const float4*)(x + b0 * 120);
    float4* L4 = (float4*)Lw;
    if (lane < nrows * 30) L4[lane] = src4[lane];
  }
  __syncthreads();

  const bool act = (s < 24) && (g < nrows);

  // ---- Phase B: per-lane feature computation ----
  int ib = g * 120 + s * 5;
  float open_ = Lw[ib + 0];
  float high  = Lw[ib + 1];
  float low   = Lw[ib + 2];
  float close = Lw[ib + 3];
  float volume= Lw[ib + 4];
  if (!act) { open_ = 0.f; high = 0.f; low = 0.f; close = 1.f; volume = 0.f; }

  float f[23];

  float lc = __logf(close + EPS);
  float lc1 = shift1_dpp(lc, s);
  float ret = (s >= 1) ? (lc - lc1) : 0.f;

  f[0] = open_; f[1] = high; f[2] = low; f[3] = close; f[4] = volume;
  f[5] = ret;   f[6] = fabsf(ret);
  float ice = 1.0f / (close + EPS);
  f[7] = (high - low) * ice;
  f[8] = fabsf(open_ - close) * ice;

  // EMAs: ema[s] = scan(x * beta^s) * (1-beta) / (1 - beta^(s+1))
  const float L2B3  = -1.0f;                    // log2(1/2)
  const float L2B6  = -0.48542682717024176f;    // log2(5/7)
  const float L2B12 = -0.24100810933089442f;    // log2(11/13)
  const float L2B24 = -0.12029423371771609f;    // log2(23/25)
  float sf = (float)s;
  float w3  = exp2f(L2B3  * sf);
  float w6  = exp2f(L2B6  * sf);
  float w12 = exp2f(L2B12 * sf);
  float w24 = exp2f(L2B24 * sf);

  float e3  = scan32_dpp(close * w3 ) * (0.5f)       / (1.f - w3  * 0.5f);
  float e6  = scan32_dpp(close * w6 ) * (2.f / 7.f)  / (1.f - w6  * (5.f / 7.f));
  float e12 = scan32_dpp(close * w12) * (2.f / 13.f) / (1.f - w12 * (11.f / 13.f));
  float e24 = scan32_dpp(close * w24) * (2.f / 25.f) / (1.f - w24 * (23.f / 25.f));
  float v6  = scan32_dpp(volume * w6 ) * (2.f / 7.f)  / (1.f - w6  * (5.f / 7.f));
  float v12 = scan32_dpp(volume * w12) * (2.f / 13.f) / (1.f - w12 * (11.f / 13.f));

  float icl = 1.0f / close;
  f[9]  = e3  * icl;
  f[10] = e6  * icl;
  f[11] = e12 * icl;
  f[12] = e24 * icl;
  float iv = 1.0f / (volume + EPS);
  f[13] = v6  * iv;
  f[14] = v12 * iv;
  f[15] = __logf(1.f + volume);

  float ang = (float)(M_PI / 12.0) * sf;  // 2*pi*s/24
  f[16] = __sinf(ang);
  f[17] = __cosf(ang);

  float lc3 = __shfl_up(lc, 3, 32);
  float lc6 = __shfl_up(lc, 6, 32);
  f[18] = (s >= 3) ? (lc - lc3) : 0.f;
  f[19] = (s >= 6) ? (lc - lc6) : 0.f;
  f[20] = (close - e12) / (e12 + EPS);

  // RSI: window-14 moving average of gains/losses with left replicate-pad.
  float cl1 = shift1_dpp(close, s);
  float delta = (s >= 1) ? (close - cl1) : 0.f;
  float gain  = fmaxf(delta, 0.f);
  float lossv = fmaxf(-delta, 0.f);
  float Pg = scan32_dpp(gain);
  float Pl = scan32_dpp(lossv);
  float Pg14 = __shfl_up(Pg, 14, 32);
  float Pl14 = __shfl_up(Pl, 14, 32);
  float g1 = __shfl(gain, 1, 32);   // first delta's gain
  float l1 = __shfl(lossv, 1, 32);
  float cnt = (float)(14 - s);
  float ag = (s >= 14) ? (Pg - Pg14) : (Pg + cnt * g1);
  float al = (s >= 14) ? (Pl - Pl14) : (Pl + cnt * l1);
  ag *= (1.f / 14.f);
  al *= (1.f / 14.f);
  float rs  = ag / (al + EPS);
  float rsi = 100.f - 100.f / (1.f + rs);
  float rsi1 = __shfl(rsi, 1, 32);  // edge pad: rsi[0] = rsi at d=0
  f[21] = (s == 0) ? rsi1 : rsi;

  // OBV
  float mult = (delta > 0.f) ? 1.f : ((delta < 0.f) ? -1.f : 0.f);
  f[22] = scan32_dpp(volume * mult);

  // ---- Phase C: stage RAW features to LDS in output layout [g][s][25] ----
  __syncthreads();  // all lanes done reading the input staging region
  if (act) {
    int ob = g * 600 + s * 25;
#pragma unroll
    for (int c = 0; c < 23; c++) Lw[ob + c] = f[c];
    // channels 23/24 are constant over s -> instance norm gives 0; stats lanes write 0s
  }
  __syncthreads();

  // ---- Stats phase: lane < 50 owns (g', c'); normalize channel in-place ----
  if (lane < 50) {
    int gp = lane >= 25 ? 1 : 0;
    int cp = lane - gp * 25;
    if (gp < nrows) {
      float* base = Lw + gp * 600 + cp;
      if (cp >= 23) {
#pragma unroll
        for (int s2 = 0; s2 < 24; ++s2) base[s2 * 25] = 0.f;
      } else {
        float vbuf[24];
#pragma unroll
        for (int s2 = 0; s2 < 24; ++s2) vbuf[s2] = base[s2 * 25];
        float sum = 0.f;
#pragma unroll
        for (int s2 = 0; s2 < 24; ++s2) sum += vbuf[s2];
        float mean = sum * (1.f / 24.f);
        float vs = 0.f;
#pragma unroll
        for (int s2 = 0; s2 < 24; ++s2) { float d = vbuf[s2] - mean; vs += d * d; }
        float rsig = rsqrtf(vs * (1.f / 24.f) + IN_EPS);
#pragma unroll
        for (int s2 = 0; s2 < 24; ++s2) base[s2 * 25] = (vbuf[s2] - mean) * rsig;
      }
    }
  }
  __syncthreads();

  // ---- Phase D: coalesced LDS -> global (nrows*150 float4) ----
  if (nrows > 0) {
    float4* dst4 = (float4*)(out + b0 * 600);
    const float4* L4o = (const float4*)Lw;
    int n4 = nrows * 150;
#pragma unroll
    for (int k = lane; k < 300; k += 64) {
      if (k < n4) dst4[k] = L4o[k];
    }
  }
}

extern "C" void kernel_launch(void* const* d_in, const int* in_sizes, int n_in,
                              void* d_out, int out_size, void* d_ws, size_t ws_size,
                              hipStream_t stream) {
  const float* x = (const float*)d_in[0];
  float* out = (float*)d_out;
  int B = in_sizes[0] / 120;          // rows of (24,5)
  int blocks = (B + 7) / 8;           // 8 rows per 256-thread block (2 per wave)
  feat_in_kernel<<<blocks, 256, 0, stream>>>(x, out, B);
}